// Round 6
// baseline (309.103 us; speedup 1.0000x reference)
//
#include <hip/hip_runtime.h>
#include <hip/hip_bf16.h>

// GraphConvolution: agg[i] = weighted-mean over edges with src=i of feat[dst]; out = relu(agg @ W + b)
// N=50000, E=1600000, D=U=128, fp32 in/out. (Requires dst < 65536, N % 16 == 0, E % 4 == 0.)
//
// R15: R11's minimal direct scatter, re-tried with the single variable that killed it fixed.
// R11 evidence: scatter with NONTEMPORAL 4B stores = full-line write-through (WRITE_SIZE
// 100MB for a 6.4MB payload, 800 GB/s, 140us; VALUBusy 0.4% -> stores, not atomics, were
// the cost). R15 uses REGULAR cached stores: the 16MB pay4 region interleaves to ~2MB per
// XCD L2 (resident), so scattered 4B stores hit-merge in L2 and evict once (~16MB).
// Preprocessing becomes one atomic + one cached 4B store per edge -- no staging round-trip,
// no LDS hist/scan/sort passes (R10's chain was ~90us of sort machinery for the same job).
// agg REVERTED to the R10 flat form (proven 70us): R14 showed dst-quartile blocking halves
// FETCH (216->106MB) but fragments segments (mean 8 edges), collapsing the 8-deep pipeline
// and in-flight demand -> 122us. Flat ~3.3 TB/s delivered is the better operating point.
// Ledger: no NT scattered stores (R11), no LDS float atomics (R12), no grid.sync (R13),
// no segment fragmentation (R14).

typedef unsigned int vuint4 __attribute__((ext_vector_type(4)));
typedef short bf16x8 __attribute__((ext_vector_type(8)));
typedef float f32x4 __attribute__((ext_vector_type(4)));
typedef float f32x2 __attribute__((ext_vector_type(2)));

#define NCAP 80                 // payload slots per node; deg ~ Poisson(32), +8.5 sigma
#define CVT_NBLK 512
#define AGG_NBLK 2048           // agg: exactly fills 256 CU x 4 SIMD x 8 waves

__device__ __forceinline__ unsigned short f2bf(float f) {
    unsigned u = __float_as_uint(f);
    unsigned r = (u + 0x7fff + ((u >> 16) & 1)) >> 16;   // RNE
    return (unsigned short)r;
}
__device__ __forceinline__ float bf2f(unsigned short h) {
    return __uint_as_float(((unsigned)h) << 16);
}

// K1 cvt: feat fp32 -> featb bf16; W -> WT bf16 (transposed); zero pay4 (full-line NT,
// contiguous -- fine); zero deg.
__global__ __launch_bounds__(256)
void cvt_kernel(const float* __restrict__ feat, ushort* __restrict__ featb,
                const float* __restrict__ W, ushort* __restrict__ WT,
                unsigned* __restrict__ pay4, int* __restrict__ deg, int N, int D) {
    int gid = blockIdx.x * 256 + threadIdx.x;
    int gstr = CVT_NBLK * 256;

    int nf4 = N * D / 4;
    for (int i = gid; i < nf4; i += gstr) {
        float4 v = ((const float4*)feat)[i];
        ushort4 r;
        r.x = f2bf(v.x); r.y = f2bf(v.y); r.z = f2bf(v.z); r.w = f2bf(v.w);
        ((ushort4*)featb)[i] = r;
    }

    int nw = D * D;
    for (int i = gid; i < nw; i += gstr) {
        int u = i >> 7, k = i & 127;
        WT[i] = f2bf(W[k * 128 + u]);   // WT[u][k] = W[k][u]
    }

    int nz4 = N * NCAP / 4;             // 1,000,000 vuint4 (contiguous full lines)
    vuint4 z = (vuint4){0u, 0u, 0u, 0u};
    for (int i = gid; i < nz4; i += gstr)
        __builtin_nontemporal_store(z, (vuint4*)pay4 + i);

    for (int i = gid; i < N; i += gstr) deg[i] = 0;
}

// K2 scatter: pos = atomicAdd(deg[src]); REGULAR cached 4B store into the node's fixed
// 320B region (L2-resident -> hit-merge, single eviction). Order within a node arbitrary.
__global__ __launch_bounds__(256)
void scatter_kernel(const int* __restrict__ esrc, const int* __restrict__ edst,
                    const float* __restrict__ ew, int* __restrict__ deg,
                    unsigned* __restrict__ pay4, int E) {
    int i4 = blockIdx.x * 256 + threadIdx.x;
    if (i4 * 4 >= E) return;
    int4 s = ((const int4*)esrc)[i4];
    int4 d = ((const int4*)edst)[i4];
    float4 w = ((const float4*)ew)[i4];
    #pragma unroll
    for (int k = 0; k < 4; ++k) {
        int sv = (k == 0) ? s.x : (k == 1) ? s.y : (k == 2) ? s.z : s.w;
        int dv = (k == 0) ? d.x : (k == 1) ? d.y : (k == 2) ? d.z : d.w;
        float wv = (k == 0) ? w.x : (k == 1) ? w.y : (k == 2) ? w.z : w.w;
        int pos = atomicAdd(&deg[sv], 1);
        if (pos < NCAP) {
            unsigned pk = ((unsigned)f2bf(wv) << 16) | (unsigned)(dv & 0xffff);
            pay4[sv * NCAP + pos] = pk;          // cached store (NOT nontemporal)
        }
    }
}

// K3 agg (R10 flat form, proven 70us): one wave per node, grid-strided over 8192 waves.
// Lane owns features (2L,2L+1). Segment = [n*NCAP, n*NCAP + pad8(deg)); pads have w=0.
// Payload software-pipelined; 8 coalesced 256B-row gathers in flight; packed f32 FMA.
__global__ __launch_bounds__(256, 8)
void agg_kernel(const ushort* __restrict__ featb, const unsigned* __restrict__ pay4,
                const int* __restrict__ deg, ushort* __restrict__ aggb, int N) {
    int tid = threadIdx.x, lane = tid & 63, wid = tid >> 6;
    const ushort2* feat2 = (const ushort2*)featb;
    ushort2* agg2 = (ushort2*)aggb;

    const int NW = AGG_NBLK * 4;                 // 8192 waves total
    for (int n = blockIdx.x * 4 + wid; n < N; n += NW) {
        int dn = deg[n]; if (dn > NCAP) dn = NCAP;
        int p = n * NCAP;
        int pend = p + ((dn + 7) & ~7);
        f32x2 axy = (f32x2){0.f, 0.f};
        float wsum = 0.f;

        if (p < pend) {
            vuint4 qa = __builtin_nontemporal_load((const vuint4*)(pay4 + p));
            vuint4 qb = __builtin_nontemporal_load((const vuint4*)(pay4 + p + 4));
            while (p < pend) {
                p += 8;
                vuint4 na, nb;
                bool more = p < pend;
                if (more) {                      // prefetch next chunk's payload first
                    na = __builtin_nontemporal_load((const vuint4*)(pay4 + p));
                    nb = __builtin_nontemporal_load((const vuint4*)(pay4 + p + 4));
                }
                unsigned q[8] = {qa.x, qa.y, qa.z, qa.w, qb.x, qb.y, qb.z, qb.w};
                unsigned fu[8];
                #pragma unroll
                for (int k = 0; k < 8; ++k)      // 8 coalesced 256B-row gathers in flight
                    fu[k] = *(const unsigned*)&feat2[(q[k] & 0xffffu) * 64 + lane];
                #pragma unroll
                for (int k = 0; k < 8; ++k) {
                    float w = __uint_as_float(q[k] & 0xffff0000u);   // pads have w=0
                    f32x2 f;
                    f.x = __uint_as_float(fu[k] << 16);
                    f.y = __uint_as_float(fu[k] & 0xffff0000u);
                    axy += w * f;                 // v_pk_fma_f32
                    wsum += w;
                }
                qa = na; qb = nb;
            }
        }
        float inv = 1.f / fmaxf(wsum, 1e-12f);
        ushort2 o;
        o.x = f2bf(axy.x * inv);
        o.y = f2bf(axy.y * inv);
        agg2[(size_t)n * 64 + lane] = o;          // L2-resident for gemm
    }
}

// K4 gemm: out = relu(agg @ W + b) via mfma_f32_16x16x32_bf16. One wave per 16-row tile.
__global__ __launch_bounds__(256)
void gemm_kernel(const ushort* __restrict__ aggb, const ushort* __restrict__ WT,
                 const float* __restrict__ bias, float* __restrict__ out, int ntiles) {
    int tid = threadIdx.x, lane = tid & 63, wid = tid >> 6;
    int tile = blockIdx.x * 4 + wid;
    if (tile >= ntiles) return;
    int m = lane & 15, quad = lane >> 4;

    f32x4 acc[8];
    #pragma unroll
    for (int t = 0; t < 8; ++t) acc[t] = (f32x4){0.f, 0.f, 0.f, 0.f};

    #pragma unroll
    for (int ks = 0; ks < 4; ++ks) {
        bf16x8 a = *(const bf16x8*)(aggb + ((size_t)(tile * 16 + m) * 128 + ks * 32 + quad * 8));
        #pragma unroll
        for (int nt = 0; nt < 8; ++nt) {
            bf16x8 bfr = *(const bf16x8*)(WT + ((nt * 16 + m) * 128 + ks * 32 + quad * 8));
            acc[nt] = __builtin_amdgcn_mfma_f32_16x16x32_bf16(a, bfr, acc[nt], 0, 0, 0);
        }
    }

    #pragma unroll
    for (int nt = 0; nt < 8; ++nt) {
        int col = nt * 16 + m;
        float bv = bias[col];
        #pragma unroll
        for (int r = 0; r < 4; ++r) {
            int row = tile * 16 + quad * 4 + r;
            float v = fmaxf(acc[nt][r] + bv, 0.f);
            __builtin_nontemporal_store(v, out + (size_t)row * 128 + col);
        }
    }
}

extern "C" void kernel_launch(void* const* d_in, const int* in_sizes, int n_in,
                              void* d_out, int out_size, void* d_ws, size_t ws_size,
                              hipStream_t stream) {
    const float* feat = (const float*)d_in[0];
    const int*   esrc = (const int*)d_in[1];
    const int*   edst = (const int*)d_in[2];
    const float* ew   = (const float*)d_in[3];
    const float* W    = (const float*)d_in[4];
    const float* bias = (const float*)d_in[5];
    float* out = (float*)d_out;

    const int D = 128;
    int N = in_sizes[0] / D;                // 50000
    int E = in_sizes[1];                    // 1600000

    // ws: deg int[N] (200KB) | pay4 u32[N*NCAP] (16MB) | featb bf16[N*D] (12.8MB) |
    //     aggb bf16[N*D] (12.8MB) | WT bf16[D*D]   (~42MB total)
    int* deg = (int*)d_ws;
    unsigned* pay4 = (unsigned*)(deg + N);
    ushort* featb = (ushort*)(pay4 + (size_t)N * NCAP);
    ushort* aggb  = featb + (size_t)N * D;
    ushort* WT    = aggb + (size_t)N * D;

    cvt_kernel<<<CVT_NBLK, 256, 0, stream>>>(feat, featb, W, WT, pay4, deg, N, D);
    scatter_kernel<<<(E / 4 + 255) / 256, 256, 0, stream>>>(esrc, edst, ew, deg, pay4, E);
    agg_kernel<<<AGG_NBLK, 256, 0, stream>>>(featb, pay4, deg, aggb, N);
    int ntiles = N / 16;
    gemm_kernel<<<(ntiles + 3) / 4, 256, 0, stream>>>(aggb, WT, bias, out, ntiles);
}

// Round 7
// 295.460 us; speedup vs baseline: 1.0462x; 1.0462x over previous
//
#include <hip/hip_runtime.h>
#include <hip/hip_bf16.h>

// GraphConvolution: agg[i] = weighted-mean over edges with src=i of feat[dst]; out = relu(agg @ W + b)
// N=50000, E=1600000, D=U=128, fp32 in/out. (Requires dst < 65536, N % 16 == 0, E % 4 == 0.)
//
// R16: bucket pipeline, de-fatted. Law refined by R11/R15: scattered sub-line stores are OK
// iff confined to a per-block window that completes while L2-resident (finB's 47KB windows);
// whole-graph scatter is write-through (2x proven: NT and cached both ~100MB WRITE). So the
// two-level bucket structure stays; its cost (4 LDS-atomic passes at 2 blocks/CU) is cut:
//  1) K1 sortA at 2048 blocks (8/CU, 8 waves/SIMD -> 4x latency hiding for hist+rank LDS
//     atomics). Placement via R14's proven global-cursor reservation; bucket hot-front
//     writes stay line-resident in L2.
//  2) deg[] computed in K1's hist pass with FIRE-AND-FORGET global atomics (no return, no
//     latency chain; 32/address). K2 scans deg directly -> finB's LDS-atomic hist pass
//     over staged records is DELETED.
//  3) K2 = scan + zero-pads + one LDS-atomic ranking pass + window-confined pay4 writes.
// agg (R10-exact: flat, wave/node, 8-deep pipeline, 3.3 TB/s pattern ceiling) and gemm
// unchanged. Ledger: no whole-graph scatter (R11/R15), no LDS float atomics (R12), no
// grid.sync (R13), no segment fragmentation (R14 quartiles).

typedef unsigned int vuint4 __attribute__((ext_vector_type(4)));
typedef short bf16x8 __attribute__((ext_vector_type(8)));
typedef float f32x4 __attribute__((ext_vector_type(4)));
typedef float f32x2 __attribute__((ext_vector_type(2)));

#define SRCSH 8                 // superbucket = src >> 8 (256 nodes/bucket)
#define BNODES 256
#define BCAP 9728               // staging cap/bucket: mean 8163, +17 sigma
#define PCAP 11776              // pay4 cap/bucket: mean 8163 + ~896 pads, +29 sigma
#define NBLK 2048               // K1 blocks: 8/CU -> 8 waves/SIMD for LDS-atomic hiding
#define AGG_NBLK 2048           // agg: exactly fills 256 CU x 4 SIMD x 8 waves

__device__ __forceinline__ unsigned short f2bf(float f) {
    unsigned u = __float_as_uint(f);
    unsigned r = (u + 0x7fff + ((u >> 16) & 1)) >> 16;   // RNE
    return (unsigned short)r;
}
__device__ __forceinline__ float bf2f(unsigned short h) {
    return __uint_as_float(((unsigned)h) << 16);
}

// K1 sortA: cvt feat->bf16 + W->WT; per-block LDS bucket hist (+ fire-and-forget deg[]);
// reserve dense bucket range via one global atomicAdd per (block,bucket); rank + place
// (w_fp32<<32 | src8<<16 | dst16) into bucket-dense staging.
__global__ __launch_bounds__(256, 8)
void sortA_kernel(const float* __restrict__ feat, ushort* __restrict__ featb,
                  const float* __restrict__ W, ushort* __restrict__ WT,
                  const int* __restrict__ esrc, const int* __restrict__ edst,
                  const float* __restrict__ ew, int* __restrict__ gcur,
                  int* __restrict__ deg, unsigned long long* __restrict__ staging,
                  int E, int nbuk, int N, int D) {
    __shared__ int hcnt[256];
    __shared__ int base[256];
    int tid = threadIdx.x, blk = blockIdx.x;

    {   // conversions (grid-strided over whole problem)
        int gid = blk * 256 + tid, gstr = NBLK * 256;
        int nf4 = N * D / 4;
        for (int i = gid; i < nf4; i += gstr) {
            float4 v = ((const float4*)feat)[i];
            ushort4 r;
            r.x = f2bf(v.x); r.y = f2bf(v.y); r.z = f2bf(v.z); r.w = f2bf(v.w);
            ((ushort4*)featb)[i] = r;
        }
        for (int i = gid; i < D * D; i += gstr) {
            int u = i >> 7, k = i & 127;
            WT[i] = f2bf(W[k * 128 + u]);   // WT[u][k] = W[k][u]
        }
    }

    hcnt[tid] = 0;
    __syncthreads();

    int per = ((E + NBLK - 1) / NBLK + 3) & ~3;   // 784
    int lo = blk * per;
    int hi = lo + per; if (hi > E) hi = E;

    // pass 1: bucket histogram (LDS, no-return) + per-node degree (global, fire-and-forget)
    for (int i4 = (lo >> 2) + tid; i4 < (hi >> 2); i4 += 256) {
        int4 s = ((const int4*)esrc)[i4];
        atomicAdd(&hcnt[s.x >> SRCSH], 1); atomicAdd(&deg[s.x], 1);
        atomicAdd(&hcnt[s.y >> SRCSH], 1); atomicAdd(&deg[s.y], 1);
        atomicAdd(&hcnt[s.z >> SRCSH], 1); atomicAdd(&deg[s.z], 1);
        atomicAdd(&hcnt[s.w >> SRCSH], 1); atomicAdd(&deg[s.w], 1);
    }
    __syncthreads();

    // reserve dense range per bucket (one global atomic per non-empty (block,bucket))
    if (tid < nbuk) base[tid] = (hcnt[tid] > 0) ? atomicAdd(&gcur[tid], hcnt[tid]) : 0;
    __syncthreads();
    hcnt[tid] = 0;              // reuse as rank cursor
    __syncthreads();

    // pass 2: re-read chunk (L2-hot, ~9KB) and place dense at the bucket's hot front
    for (int i4 = (lo >> 2) + tid; i4 < (hi >> 2); i4 += 256) {
        int4 s = ((const int4*)esrc)[i4];
        int4 d = ((const int4*)edst)[i4];
        float4 w = ((const float4*)ew)[i4];
        #pragma unroll
        for (int k = 0; k < 4; ++k) {
            int sv = (k == 0) ? s.x : (k == 1) ? s.y : (k == 2) ? s.z : s.w;
            int dv = (k == 0) ? d.x : (k == 1) ? d.y : (k == 2) ? d.z : d.w;
            float wv = (k == 0) ? w.x : (k == 1) ? w.y : (k == 2) ? w.z : w.w;
            int b = sv >> SRCSH;
            int r = base[b] + atomicAdd(&hcnt[b], 1);
            if (r < BCAP) {
                unsigned long long v = ((unsigned long long)__float_as_uint(wv) << 32)
                                     | ((unsigned long long)(sv & (BNODES - 1)) << 16)
                                     | (unsigned long long)(unsigned)(dv & 0xffff);
                staging[(size_t)b * BCAP + r] = v;
            }
        }
    }
}

// K2 place: one block per bucket. Scan deg (NO hist pass -- deg known globally), write
// rs/re + zero pads, then one LDS-atomic ranking pass scattering 4B payloads into the
// bucket's ~47KB pay4 window (L2-resident, write-merges -- the proven-safe pattern).
__global__ __launch_bounds__(256)
void place_kernel(const int* __restrict__ gcur, const int* __restrict__ deg,
                  const unsigned long long* __restrict__ staging,
                  unsigned* __restrict__ pay4, int* __restrict__ rs, int* __restrict__ re,
                  int N) {
    __shared__ int cur[256];
    __shared__ int ws4[4];
    int b = blockIdx.x, tid = threadIdx.x, lane = tid & 63, wid = tid >> 6;

    int n = b * BNODES + tid;
    int d = (n < N) ? deg[n] : 0;
    int p = (d + 7) & ~7;

    // 256-thread exclusive scan of padded degrees
    int x = p;
    #pragma unroll
    for (int off = 1; off < 64; off <<= 1) {
        int y = __shfl_up(x, off, 64);
        if (lane >= off) x += y;
    }
    if (lane == 63) ws4[wid] = x;
    __syncthreads();
    if (tid == 0) { int a = 0; for (int w = 0; w < 4; ++w) { int t = ws4[w]; ws4[w] = a; a += t; } }
    __syncthreads();
    int excl = ws4[wid] + x - p;

    int gb = b * PCAP;
    cur[tid] = excl;
    if (n < N) { rs[n] = gb + excl; re[n] = gb + excl + p; }
    for (int i = excl + d; i < excl + p && i < PCAP; ++i) pay4[gb + i] = 0;  // zero-weight pads
    __syncthreads();

    int m = gcur[b]; if (m > BCAP) m = BCAP;
    size_t sbase = (size_t)b * BCAP;
    for (int i = tid; i < m; i += 256) {
        unsigned long long v = staging[sbase + i];
        int s8 = (int)((v >> 16) & (BNODES - 1));
        int pos = atomicAdd(&cur[s8], 1);
        unsigned wbf = f2bf(__uint_as_float((unsigned)(v >> 32)));
        if (pos < PCAP) pay4[gb + pos] = (wbf << 16) | (unsigned)(v & 0xffffu);
    }
}

// K3 agg (R10-exact, proven 70us): one wave per node, grid-strided over 8192 waves.
// Lane owns features (2L,2L+1). Segments x8-padded; pads have w=0. Payload software-
// pipelined; 8 coalesced 256B-row gathers in flight; packed f32 FMA.
__global__ __launch_bounds__(256, 8)
void agg_kernel(const ushort* __restrict__ featb, const unsigned* __restrict__ pay4,
                const int* __restrict__ rs, const int* __restrict__ re,
                ushort* __restrict__ aggb, int N) {
    int tid = threadIdx.x, lane = tid & 63, wid = tid >> 6;
    const ushort2* feat2 = (const ushort2*)featb;
    ushort2* agg2 = (ushort2*)aggb;

    const int NW = AGG_NBLK * 4;                 // 8192 waves total
    for (int n = blockIdx.x * 4 + wid; n < N; n += NW) {
        int p = rs[n], pend = re[n];
        f32x2 axy = (f32x2){0.f, 0.f};
        float wsum = 0.f;

        if (p < pend) {
            vuint4 qa = __builtin_nontemporal_load((const vuint4*)(pay4 + p));
            vuint4 qb = __builtin_nontemporal_load((const vuint4*)(pay4 + p + 4));
            while (p < pend) {
                p += 8;
                vuint4 na, nb;
                bool more = p < pend;
                if (more) {                      // prefetch next chunk's payload first
                    na = __builtin_nontemporal_load((const vuint4*)(pay4 + p));
                    nb = __builtin_nontemporal_load((const vuint4*)(pay4 + p + 4));
                }
                unsigned q[8] = {qa.x, qa.y, qa.z, qa.w, qb.x, qb.y, qb.z, qb.w};
                unsigned fu[8];
                #pragma unroll
                for (int k = 0; k < 8; ++k)      // 8 coalesced 256B-row gathers in flight
                    fu[k] = *(const unsigned*)&feat2[(q[k] & 0xffffu) * 64 + lane];
                #pragma unroll
                for (int k = 0; k < 8; ++k) {
                    float w = __uint_as_float(q[k] & 0xffff0000u);   // pads have w=0
                    f32x2 f;
                    f.x = __uint_as_float(fu[k] << 16);
                    f.y = __uint_as_float(fu[k] & 0xffff0000u);
                    axy += w * f;                 // v_pk_fma_f32
                    wsum += w;
                }
                qa = na; qb = nb;
            }
        }
        float inv = 1.f / fmaxf(wsum, 1e-12f);
        ushort2 o;
        o.x = f2bf(axy.x * inv);
        o.y = f2bf(axy.y * inv);
        agg2[(size_t)n * 64 + lane] = o;          // L2-resident for gemm
    }
}

// K4 gemm: out = relu(agg @ W + b) via mfma_f32_16x16x32_bf16. One wave per 16-row tile.
__global__ __launch_bounds__(256)
void gemm_kernel(const ushort* __restrict__ aggb, const ushort* __restrict__ WT,
                 const float* __restrict__ bias, float* __restrict__ out, int ntiles) {
    int tid = threadIdx.x, lane = tid & 63, wid = tid >> 6;
    int tile = blockIdx.x * 4 + wid;
    if (tile >= ntiles) return;
    int m = lane & 15, quad = lane >> 4;

    f32x4 acc[8];
    #pragma unroll
    for (int t = 0; t < 8; ++t) acc[t] = (f32x4){0.f, 0.f, 0.f, 0.f};

    #pragma unroll
    for (int ks = 0; ks < 4; ++ks) {
        bf16x8 a = *(const bf16x8*)(aggb + ((size_t)(tile * 16 + m) * 128 + ks * 32 + quad * 8));
        #pragma unroll
        for (int nt = 0; nt < 8; ++nt) {
            bf16x8 bfr = *(const bf16x8*)(WT + ((nt * 16 + m) * 128 + ks * 32 + quad * 8));
            acc[nt] = __builtin_amdgcn_mfma_f32_16x16x32_bf16(a, bfr, acc[nt], 0, 0, 0);
        }
    }

    #pragma unroll
    for (int nt = 0; nt < 8; ++nt) {
        int col = nt * 16 + m;
        float bv = bias[col];
        #pragma unroll
        for (int r = 0; r < 4; ++r) {
            int row = tile * 16 + quad * 4 + r;
            float v = fmaxf(acc[nt][r] + bv, 0.f);
            __builtin_nontemporal_store(v, out + (size_t)row * 128 + col);
        }
    }
}

extern "C" void kernel_launch(void* const* d_in, const int* in_sizes, int n_in,
                              void* d_out, int out_size, void* d_ws, size_t ws_size,
                              hipStream_t stream) {
    const float* feat = (const float*)d_in[0];
    const int*   esrc = (const int*)d_in[1];
    const int*   edst = (const int*)d_in[2];
    const float* ew   = (const float*)d_in[3];
    const float* W    = (const float*)d_in[4];
    const float* bias = (const float*)d_in[5];
    float* out = (float*)d_out;

    const int D = 128;
    int N = in_sizes[0] / D;                    // 50000
    int E = in_sizes[1];                        // 1600000
    int nbuk = (N + BNODES - 1) >> SRCSH;       // 196

    // ws: staging u64[nbuk*BCAP] (15.3MB) | pay4 u32[nbuk*PCAP] (9.2MB) | rs[N] | re[N] |
    //     gcur[256] | deg[N] | featb (12.8MB) | WT (32KB)  (~38MB).
    //     aggb ALIASES staging (dead after K2 place reads it).
    unsigned long long* staging = (unsigned long long*)d_ws;
    unsigned* pay4 = (unsigned*)(staging + (size_t)nbuk * BCAP);
    int* rs   = (int*)(pay4 + (size_t)nbuk * PCAP);
    int* re   = rs + N;
    int* gcur = re + N;
    int* deg  = gcur + 256;
    ushort* featb = (ushort*)(deg + N);
    ushort* WT    = featb + (size_t)N * D;
    ushort* aggb  = (ushort*)staging;           // alias (12.8MB <= 15.3MB)

    hipMemsetAsync(gcur, 0, (256 + (size_t)N) * sizeof(int), stream);   // gcur + deg
    sortA_kernel<<<NBLK, 256, 0, stream>>>(feat, featb, W, WT, esrc, edst, ew,
                                           gcur, deg, staging, E, nbuk, N, D);
    place_kernel<<<nbuk, 256, 0, stream>>>(gcur, deg, staging, pay4, rs, re, N);
    agg_kernel<<<AGG_NBLK, 256, 0, stream>>>(featb, pay4, rs, re, aggb, N);
    int ntiles = N / 16;
    gemm_kernel<<<(ntiles + 3) / 4, 256, 0, stream>>>(aggb, WT, bias, out, ntiles);
}

// Round 9
// 268.230 us; speedup vs baseline: 1.1524x; 1.1015x over previous
//
#include <hip/hip_runtime.h>
#include <hip/hip_bf16.h>

// GraphConvolution: agg[i] = weighted-mean over edges with src=i of feat[dst]; out = relu(agg @ W + b)
// N=50000, E=1600000, D=U=128, fp32 in/out. (Requires dst < 65536, N % 16 == 0, E % 4 == 0.)
//
// R17 (resubmit; R8's bench was an infra failure "container failed twice" -- no counters, no
// verdict): R16's merged structure at R9's proven write geometry. R16 failure isolated:
// NBLK=2048 shrank per-(block,bucket) reservations to 4 edges = 32B < cacheline -> sub-line
// scattered stores, 6x write amplification (WRITE 84MB, 110us store-bound). LAW (final form):
// scattered stores are safe iff each block owns an exclusive DENSE range >= 128B written
// within us. NBLK=512 restores 16-edge/128B sub-runs (R9-proven). Kept from R16: global-
// cursor range reservation (deletes scanB dispatch + one esrc HBM pass), fire-and-forget
// deg[] atomics in the hist pass (deletes finB's 8163-record LDS-atomic hist pass). 512
// threads in sortA and place to halve the LDS-atomic-return chains. agg is R10-exact
// (proven 70us, pattern-ceiling-bound at ~3.3 TB/s); gemm unchanged.
// Ledger: no whole-graph scatter (R11/R15), no LDS float atomics (R12), no grid.sync (R13),
// no segment fragmentation (R14), no sub-128B write ranges (R16).

typedef unsigned int vuint4 __attribute__((ext_vector_type(4)));
typedef short bf16x8 __attribute__((ext_vector_type(8)));
typedef float f32x4 __attribute__((ext_vector_type(4)));
typedef float f32x2 __attribute__((ext_vector_type(2)));

#define SRCSH 8                 // superbucket = src >> 8 (256 nodes/bucket)
#define BNODES 256
#define BCAP 9728               // staging cap/bucket: mean 8163, +17 sigma
#define PCAP 11776              // pay4 cap/bucket: mean 8163 + ~896 pads
#define NBLK 512                // sortA blocks: 16-edge = 128B sub-runs (R9-proven geometry)
#define AGG_NBLK 2048           // agg: exactly fills 256 CU x 4 SIMD x 8 waves

__device__ __forceinline__ unsigned short f2bf(float f) {
    unsigned u = __float_as_uint(f);
    unsigned r = (u + 0x7fff + ((u >> 16) & 1)) >> 16;   // RNE
    return (unsigned short)r;
}
__device__ __forceinline__ float bf2f(unsigned short h) {
    return __uint_as_float(((unsigned)h) << 16);
}

// K1 sortA (512 blocks x 512 threads): cvt feat->bf16 + W->WT; per-block LDS bucket hist
// (+ fire-and-forget deg[]); reserve dense bucket range via one global atomicAdd per
// (block,bucket); rank + place (w_fp32<<32 | src8<<16 | dst16) into 128B-dense staging.
__global__ __launch_bounds__(512)
void sortA_kernel(const float* __restrict__ feat, ushort* __restrict__ featb,
                  const float* __restrict__ W, ushort* __restrict__ WT,
                  const int* __restrict__ esrc, const int* __restrict__ edst,
                  const float* __restrict__ ew, int* __restrict__ gcur,
                  int* __restrict__ deg, unsigned long long* __restrict__ staging,
                  int E, int nbuk, int N, int D) {
    __shared__ int hcnt[256];
    __shared__ int base[256];
    int tid = threadIdx.x, blk = blockIdx.x;

    {   // conversions (grid-strided over whole problem)
        int gid = blk * 512 + tid, gstr = NBLK * 512;
        int nf4 = N * D / 4;
        for (int i = gid; i < nf4; i += gstr) {
            float4 v = ((const float4*)feat)[i];
            ushort4 r;
            r.x = f2bf(v.x); r.y = f2bf(v.y); r.z = f2bf(v.z); r.w = f2bf(v.w);
            ((ushort4*)featb)[i] = r;
        }
        for (int i = gid; i < D * D; i += gstr) {
            int u = i >> 7, k = i & 127;
            WT[i] = f2bf(W[k * 128 + u]);   // WT[u][k] = W[k][u]
        }
    }

    if (tid < 256) hcnt[tid] = 0;
    __syncthreads();

    int per = ((E + NBLK - 1) / NBLK + 3) & ~3;   // 3128
    int lo = blk * per;
    int hi = lo + per; if (hi > E) hi = E;

    // pass 1: bucket histogram (LDS, no-return) + per-node degree (global, fire-and-forget)
    for (int i4 = (lo >> 2) + tid; i4 < (hi >> 2); i4 += 512) {
        int4 s = ((const int4*)esrc)[i4];
        atomicAdd(&hcnt[s.x >> SRCSH], 1); atomicAdd(&deg[s.x], 1);
        atomicAdd(&hcnt[s.y >> SRCSH], 1); atomicAdd(&deg[s.y], 1);
        atomicAdd(&hcnt[s.z >> SRCSH], 1); atomicAdd(&deg[s.z], 1);
        atomicAdd(&hcnt[s.w >> SRCSH], 1); atomicAdd(&deg[s.w], 1);
    }
    __syncthreads();

    // reserve dense range per bucket (one global atomic per non-empty (block,bucket);
    // ~16 edges = 128B per reservation -> line-resident dense writes)
    if (tid < nbuk) base[tid] = (hcnt[tid] > 0) ? atomicAdd(&gcur[tid], hcnt[tid]) : 0;
    __syncthreads();
    if (tid < 256) hcnt[tid] = 0;   // reuse as rank cursor
    __syncthreads();

    // pass 2: re-read chunk (L2-hot, ~37KB) and place dense in this block's reservations
    for (int i4 = (lo >> 2) + tid; i4 < (hi >> 2); i4 += 512) {
        int4 s = ((const int4*)esrc)[i4];
        int4 d = ((const int4*)edst)[i4];
        float4 w = ((const float4*)ew)[i4];
        #pragma unroll
        for (int k = 0; k < 4; ++k) {
            int sv = (k == 0) ? s.x : (k == 1) ? s.y : (k == 2) ? s.z : s.w;
            int dv = (k == 0) ? d.x : (k == 1) ? d.y : (k == 2) ? d.z : d.w;
            float wv = (k == 0) ? w.x : (k == 1) ? w.y : (k == 2) ? w.z : w.w;
            int b = sv >> SRCSH;
            int r = base[b] + atomicAdd(&hcnt[b], 1);
            if (r < BCAP) {
                unsigned long long v = ((unsigned long long)__float_as_uint(wv) << 32)
                                     | ((unsigned long long)(sv & (BNODES - 1)) << 16)
                                     | (unsigned long long)(unsigned)(dv & 0xffff);
                staging[(size_t)b * BCAP + r] = v;
            }
        }
    }
}

// K2 place (196 blocks x 512 threads): scan deg (no hist pass -- deg known globally),
// write rs/re + zero pads, then one LDS-atomic ranking pass scattering 4B payloads into
// the bucket's ~47KB pay4 window (block-exclusive, completes in us -> L2 write-merges).
__global__ __launch_bounds__(512)
void place_kernel(const int* __restrict__ gcur, const int* __restrict__ deg,
                  const unsigned long long* __restrict__ staging,
                  unsigned* __restrict__ pay4, int* __restrict__ rs, int* __restrict__ re,
                  int N) {
    __shared__ int cur[256];
    __shared__ int ws4[4];
    int b = blockIdx.x, tid = threadIdx.x, lane = tid & 63, wid = tid >> 6;

    int n = b * BNODES + tid;
    int d = (tid < 256 && n < N) ? deg[n] : 0;
    int p = (d + 7) & ~7;

    // exclusive scan of padded degrees over the first 256 threads (waves 0-3)
    int x = p;
    #pragma unroll
    for (int off = 1; off < 64; off <<= 1) {
        int y = __shfl_up(x, off, 64);
        if (lane >= off) x += y;
    }
    if (lane == 63 && wid < 4) ws4[wid] = x;
    __syncthreads();
    if (tid == 0) { int a = 0; for (int w = 0; w < 4; ++w) { int t = ws4[w]; ws4[w] = a; a += t; } }
    __syncthreads();

    int gb = b * PCAP;
    if (tid < 256) {
        int excl = ws4[wid] + x - p;
        cur[tid] = excl;
        if (n < N) { rs[n] = gb + excl; re[n] = gb + excl + p; }
        for (int i = excl + d; i < excl + p && i < PCAP; ++i) pay4[gb + i] = 0;  // w=0 pads
    }
    __syncthreads();

    int m = gcur[b]; if (m > BCAP) m = BCAP;
    size_t sbase = (size_t)b * BCAP;
    for (int i = tid; i < m; i += 512) {
        unsigned long long v = staging[sbase + i];
        int s8 = (int)((v >> 16) & (BNODES - 1));
        int pos = atomicAdd(&cur[s8], 1);
        unsigned wbf = f2bf(__uint_as_float((unsigned)(v >> 32)));
        if (pos < PCAP) pay4[gb + pos] = (wbf << 16) | (unsigned)(v & 0xffffu);
    }
}

// K3 agg (R10-exact, proven 70us): one wave per node, grid-strided over 8192 waves.
// Lane owns features (2L,2L+1). Segments x8-padded; pads have w=0. Payload software-
// pipelined; 8 coalesced 256B-row gathers in flight; packed f32 FMA.
__global__ __launch_bounds__(256, 8)
void agg_kernel(const ushort* __restrict__ featb, const unsigned* __restrict__ pay4,
                const int* __restrict__ rs, const int* __restrict__ re,
                ushort* __restrict__ aggb, int N) {
    int tid = threadIdx.x, lane = tid & 63, wid = tid >> 6;
    const ushort2* feat2 = (const ushort2*)featb;
    ushort2* agg2 = (ushort2*)aggb;

    const int NW = AGG_NBLK * 4;                 // 8192 waves total
    for (int n = blockIdx.x * 4 + wid; n < N; n += NW) {
        int p = rs[n], pend = re[n];
        f32x2 axy = (f32x2){0.f, 0.f};
        float wsum = 0.f;

        if (p < pend) {
            vuint4 qa = __builtin_nontemporal_load((const vuint4*)(pay4 + p));
            vuint4 qb = __builtin_nontemporal_load((const vuint4*)(pay4 + p + 4));
            while (p < pend) {
                p += 8;
                vuint4 na, nb;
                bool more = p < pend;
                if (more) {                      // prefetch next chunk's payload first
                    na = __builtin_nontemporal_load((const vuint4*)(pay4 + p));
                    nb = __builtin_nontemporal_load((const vuint4*)(pay4 + p + 4));
                }
                unsigned q[8] = {qa.x, qa.y, qa.z, qa.w, qb.x, qb.y, qb.z, qb.w};
                unsigned fu[8];
                #pragma unroll
                for (int k = 0; k < 8; ++k)      // 8 coalesced 256B-row gathers in flight
                    fu[k] = *(const unsigned*)&feat2[(q[k] & 0xffffu) * 64 + lane];
                #pragma unroll
                for (int k = 0; k < 8; ++k) {
                    float w = __uint_as_float(q[k] & 0xffff0000u);   // pads have w=0
                    f32x2 f;
                    f.x = __uint_as_float(fu[k] << 16);
                    f.y = __uint_as_float(fu[k] & 0xffff0000u);
                    axy += w * f;                 // v_pk_fma_f32
                    wsum += w;
                }
                qa = na; qb = nb;
            }
        }
        float inv = 1.f / fmaxf(wsum, 1e-12f);
        ushort2 o;
        o.x = f2bf(axy.x * inv);
        o.y = f2bf(axy.y * inv);
        agg2[(size_t)n * 64 + lane] = o;          // L2-resident for gemm
    }
}

// K4 gemm: out = relu(agg @ W + b) via mfma_f32_16x16x32_bf16. One wave per 16-row tile.
__global__ __launch_bounds__(256)
void gemm_kernel(const ushort* __restrict__ aggb, const ushort* __restrict__ WT,
                 const float* __restrict__ bias, float* __restrict__ out, int ntiles) {
    int tid = threadIdx.x, lane = tid & 63, wid = tid >> 6;
    int tile = blockIdx.x * 4 + wid;
    if (tile >= ntiles) return;
    int m = lane & 15, quad = lane >> 4;

    f32x4 acc[8];
    #pragma unroll
    for (int t = 0; t < 8; ++t) acc[t] = (f32x4){0.f, 0.f, 0.f, 0.f};

    #pragma unroll
    for (int ks = 0; ks < 4; ++ks) {
        bf16x8 a = *(const bf16x8*)(aggb + ((size_t)(tile * 16 + m) * 128 + ks * 32 + quad * 8));
        #pragma unroll
        for (int nt = 0; nt < 8; ++nt) {
            bf16x8 bfr = *(const bf16x8*)(WT + ((nt * 16 + m) * 128 + ks * 32 + quad * 8));
            acc[nt] = __builtin_amdgcn_mfma_f32_16x16x32_bf16(a, bfr, acc[nt], 0, 0, 0);
        }
    }

    #pragma unroll
    for (int nt = 0; nt < 8; ++nt) {
        int col = nt * 16 + m;
        float bv = bias[col];
        #pragma unroll
        for (int r = 0; r < 4; ++r) {
            int row = tile * 16 + quad * 4 + r;
            float v = fmaxf(acc[nt][r] + bv, 0.f);
            __builtin_nontemporal_store(v, out + (size_t)row * 128 + col);
        }
    }
}

extern "C" void kernel_launch(void* const* d_in, const int* in_sizes, int n_in,
                              void* d_out, int out_size, void* d_ws, size_t ws_size,
                              hipStream_t stream) {
    const float* feat = (const float*)d_in[0];
    const int*   esrc = (const int*)d_in[1];
    const int*   edst = (const int*)d_in[2];
    const float* ew   = (const float*)d_in[3];
    const float* W    = (const float*)d_in[4];
    const float* bias = (const float*)d_in[5];
    float* out = (float*)d_out;

    const int D = 128;
    int N = in_sizes[0] / D;                    // 50000
    int E = in_sizes[1];                        // 1600000
    int nbuk = (N + BNODES - 1) >> SRCSH;       // 196

    // ws: staging u64[nbuk*BCAP] (15.3MB) | pay4 u32[nbuk*PCAP] (9.2MB) | rs[N] | re[N] |
    //     gcur[256] | deg[N] | featb (12.8MB) | WT (32KB)  (~38MB).
    //     aggb ALIASES staging (dead after K2 place reads it).
    unsigned long long* staging = (unsigned long long*)d_ws;
    unsigned* pay4 = (unsigned*)(staging + (size_t)nbuk * BCAP);
    int* rs   = (int*)(pay4 + (size_t)nbuk * PCAP);
    int* re   = rs + N;
    int* gcur = re + N;
    int* deg  = gcur + 256;
    ushort* featb = (ushort*)(deg + N);
    ushort* WT    = featb + (size_t)N * D;
    ushort* aggb  = (ushort*)staging;           // alias (12.8MB <= 15.3MB)

    hipMemsetAsync(gcur, 0, (256 + (size_t)N) * sizeof(int), stream);   // gcur + deg
    sortA_kernel<<<NBLK, 512, 0, stream>>>(feat, featb, W, WT, esrc, edst, ew,
                                           gcur, deg, staging, E, nbuk, N, D);
    place_kernel<<<nbuk, 512, 0, stream>>>(gcur, deg, staging, pay4, rs, re, N);
    agg_kernel<<<AGG_NBLK, 256, 0, stream>>>(featb, pay4, rs, re, aggb, N);
    int ntiles = N / 16;
    gemm_kernel<<<(ntiles + 3) / 4, 256, 0, stream>>>(aggb, WT, bias, out, ntiles);
}